// Round 4
// baseline (1958.140 us; speedup 1.0000x reference)
//
#include <hip/hip_runtime.h>
#include <hip/hip_bf16.h>
#include <cstdint>
#include <cstddef>

// Problem constants
#define BSZ  256
#define TDIM 128
#define DDIM 256
#define HIDN 256
#define G3   768   // 3*HID

using bf16x8 = __attribute__((ext_vector_type(8))) short;   // 8 bf16 in 4 VGPRs
using f32x4  = __attribute__((ext_vector_type(4))) float;   // MFMA accumulator

__device__ __forceinline__ unsigned short f2bf(float f) {
  union { float f; unsigned u; } x; x.f = f;
  unsigned r = x.u + 0x7FFFu + ((x.u >> 16) & 1u);   // RNE, inputs are sane
  return (unsigned short)(r >> 16);
}
__device__ __forceinline__ float bf2f_s(unsigned short u) {
  union { unsigned u; float f; } t; t.u = ((unsigned)u) << 16; return t.f;
}
__device__ __forceinline__ float sigm(float x) {
  return __builtin_amdgcn_rcpf(1.f + __expf(-x));
}
__device__ __forceinline__ float tanh_f(float x) {
  float e = __expf(2.f * x);
  return 1.f - 2.f * __builtin_amdgcn_rcpf(e + 1.f);
}
__device__ __forceinline__ float gelu_f(float x) {
  return 0.5f * x * (1.f + erff(x * 0.70710678118654752f));
}

// ---------------- fused fp32 -> bf16 convert (P + 8 weight tensors) ----------------
__global__ __launch_bounds__(256) void cvt_all(
    const float* __restrict__ P,  unsigned short* __restrict__ Pd,
    const float* __restrict__ a0, unsigned short* __restrict__ d0,
    const float* __restrict__ a1, unsigned short* __restrict__ d1,
    const float* __restrict__ a2, unsigned short* __restrict__ d2,
    const float* __restrict__ a3, unsigned short* __restrict__ d3,
    const float* __restrict__ a4, unsigned short* __restrict__ d4,
    const float* __restrict__ a5, unsigned short* __restrict__ d5,
    const float* __restrict__ a6, unsigned short* __restrict__ d6,
    const float* __restrict__ a7, unsigned short* __restrict__ d7)
{
  const int blk = blockIdx.x;
  const float4* s; ushort4* d; int i;
  if      (blk < 8192) { s = (const float4*)P;  d = (ushort4*)Pd; i = blk * 256; }
  else if (blk < 8240) { s = (const float4*)a0; d = (ushort4*)d0; i = (blk - 8192) * 256; }
  else if (blk < 8288) { s = (const float4*)a1; d = (ushort4*)d1; i = (blk - 8240) * 256; }
  else if (blk < 8336) { s = (const float4*)a2; d = (ushort4*)d2; i = (blk - 8288) * 256; }
  else if (blk < 8384) { s = (const float4*)a3; d = (ushort4*)d3; i = (blk - 8336) * 256; }
  else if (blk < 8400) { s = (const float4*)a4; d = (ushort4*)d4; i = (blk - 8384) * 256; }
  else if (blk < 8416) { s = (const float4*)a5; d = (ushort4*)d5; i = (blk - 8400) * 256; }
  else if (blk < 8432) { s = (const float4*)a6; d = (ushort4*)d6; i = (blk - 8416) * 256; }
  else                 { s = (const float4*)a7; d = (ushort4*)d7; i = (blk - 8432) * 256; }
  i += threadIdx.x;
  float4 v = s[i];
  ushort4 o;
  o.x = f2bf(v.x); o.y = f2bf(v.y); o.z = f2bf(v.z); o.w = f2bf(v.w);
  d[i] = o;
}

// ---------------- bf16 -> fp32 expand (for Hout) ----------------
__global__ __launch_bounds__(256) void bf2f(const unsigned short* __restrict__ s,
                                            float* __restrict__ d, int n8) {
  int i = blockIdx.x * 256 + threadIdx.x;
  if (i >= n8) return;
  ushort4 a = ((const ushort4*)s)[i * 2];
  ushort4 b = ((const ushort4*)s)[i * 2 + 1];
  float4 o0, o1;
  o0.x = bf2f_s(a.x); o0.y = bf2f_s(a.y); o0.z = bf2f_s(a.z); o0.w = bf2f_s(a.w);
  o1.x = bf2f_s(b.x); o1.y = bf2f_s(b.y); o1.z = bf2f_s(b.z); o1.w = bf2f_s(b.w);
  ((float4*)d)[i * 2] = o0;
  ((float4*)d)[i * 2 + 1] = o1;
}

// ---------------- async global->LDS staging ----------------
#if defined(__has_builtin)
#if __has_builtin(__builtin_amdgcn_global_load_lds)
#define HAVE_GLL 1
#endif
#endif
#ifndef HAVE_GLL
#define HAVE_GLL 0
#endif

__device__ __forceinline__ void stage16(const unsigned short* gp,
                                        unsigned short* lbase, int lane) {
#if HAVE_GLL
  __builtin_amdgcn_global_load_lds((const __attribute__((address_space(1))) void*)gp,
                                   (__attribute__((address_space(3))) void*)lbase, 16, 0, 0);
#else
  *(bf16x8*)(lbase + lane * 8) = *(const bf16x8*)gp;
#endif
}

// ---------------- bf16 MFMA GEMM: C[m,n] = sum_k A[m,k]*B[n,k] (+bias, +gelu) ----------------
// 128x128 tile, BK=32, 256 threads (4 waves, each 64x64), chunk-major LDS (conflict-free b128).
// tiled!=0: Cf written in gru-tiled layout (see gru_rec).
__global__ __launch_bounds__(256) void gemm_bf16(
    const unsigned short* __restrict__ A, int lda,
    const unsigned short* __restrict__ B, int ldb,
    const float* __restrict__ bias,
    float* __restrict__ Cf, unsigned short* __restrict__ Cbf,
    int K, int ldc, int do_gelu, int tiled)
{
  __shared__ unsigned short As[4096], Bs[4096];   // 8KB each: [chunk c][row r] 16B slots
  const int tid = threadIdx.x;
  const int w = tid >> 6, lane = tid & 63;
  const int m16 = lane & 15, quad = lane >> 4;
  const int m0 = blockIdx.y * 128, n0 = blockIdx.x * 128;
  const int wm = w >> 1, wn = w & 1;

  const f32x4 z4 = {0.f, 0.f, 0.f, 0.f};
  f32x4 acc[4][4];
#pragma unroll
  for (int i = 0; i < 4; ++i)
#pragma unroll
    for (int j = 0; j < 4; ++j) acc[i][j] = z4;

  const int nk = K >> 5;
  for (int kk = 0; kk < nk; ++kk) {
#pragma unroll
    for (int i = 0; i < 2; ++i) {
      const int r = i * 64 + lane;                 // row within tile
      stage16(A + (size_t)(m0 + r) * lda + kk * 32 + w * 8, &As[w * 1024 + i * 512], lane);
      stage16(B + (size_t)(n0 + r) * ldb + kk * 32 + w * 8, &Bs[w * 1024 + i * 512], lane);
    }
    __syncthreads();
    bf16x8 af[4], bfr[4];
#pragma unroll
    for (int i = 0; i < 4; ++i) {
      af[i]  = *(const bf16x8*)&As[quad * 1024 + (wm * 64 + i * 16 + m16) * 8];
      bfr[i] = *(const bf16x8*)&Bs[quad * 1024 + (wn * 64 + i * 16 + m16) * 8];
    }
#pragma unroll
    for (int i = 0; i < 4; ++i)
#pragma unroll
      for (int j = 0; j < 4; ++j)
        acc[i][j] = __builtin_amdgcn_mfma_f32_16x16x32_bf16(af[i], bfr[j], acc[i][j], 0, 0, 0);
    __syncthreads();
  }

#pragma unroll
  for (int i = 0; i < 4; ++i) {
    const int row0 = m0 + wm * 64 + i * 16 + quad * 4;
#pragma unroll
    for (int j = 0; j < 4; ++j) {
      const int col = n0 + wn * 64 + j * 16 + m16;
#pragma unroll
      for (int rg = 0; rg < 4; ++rg) {
        float v = acc[i][j][rg];
        if (bias) v += bias[col];
        if (do_gelu) v = gelu_f(v);
        if (tiled) {
          const int row = row0 + rg;
          const int b = row >> 7, tt = row & 127;
          const int g = col >> 8, wq = (col >> 5) & 7, t2 = (col >> 4) & 1, mm = col & 15;
          const int c = g * 2 + t2;
          const size_t off = ((size_t)((b >> 4) * 128 + tt)) * 12288
                           + (size_t)(((c * 32 + wq * 4 + ((b & 15) >> 2)) * 16 + mm) * 4 + (b & 3));
          Cf[off] = v;
        } else {
          const size_t off = (size_t)(row0 + rg) * ldc + col;
          if (Cf)  Cf[off] = v;
          if (Cbf) Cbf[off] = f2bf(v);
        }
      }
    }
  }
}

// ---------------- GRU recurrence (one layer) ----------------
// 16 blocks x 16 batch rows; 512 threads = 8 waves, wave w owns hidden cols [32w,32w+32).
// r,z weight fragments PINNED IN AGPRS via asm "+a" (128 AGPR/lane, loaded once).
// n-gate: cols [0,80) LDS-resident (40 KB, XOR swizzle), cols [80,256) streamed from L2.
// h bf16 tile double-buffered in LDS; gi pre-tiled -> 6 coalesced float4 loads/lane/step.
__global__ __launch_bounds__(512, 2) void gru_rec(
    const float* __restrict__ gi,            // tiled (see gemm_bf16), bih already added
    const unsigned short* __restrict__ Whh,  // (768, 256) bf16
    const float* __restrict__ bhh,           // (768,)
    unsigned short* __restrict__ Hbf)        // (BS,T,HID) bf16
{
  __shared__ unsigned short hs[2][4096];     // h tile: [buf][row r][chunk c at (c^r)]
  __shared__ unsigned short ns[20480];       // n-gate cols [0,80): [col][chunk kc at (kc^(col&15))]
  const int tid = threadIdx.x;
  const int w = tid >> 6, lane = tid & 63;
  const int m16 = lane & 15, quad = lane >> 4;
  const int b0 = blockIdx.x * 16;
  const int colw = w * 32;

  for (int i = tid; i < 4096; i += 512) hs[0][i] = 0;       // h0 = 0
  for (int s = tid; s < 2560; s += 512) {                    // stage n-gate slice
    const int col = s >> 5, kc = s & 31;
    const bf16x8 v = *(const bf16x8*)&Whh[(size_t)(512 + col) * 256 + kc * 8];
    *(bf16x8*)&ns[col * 256 + ((kc ^ (col & 15)) << 3)] = v;
  }

  // r,z gate weight B-fragments -> AGPRs (asm pin: no remat, no scratch spill)
  bf16x8 wreg[2][2][8];
#pragma unroll
  for (int g = 0; g < 2; ++g)
#pragma unroll
    for (int t2 = 0; t2 < 2; ++t2)
#pragma unroll
      for (int kk = 0; kk < 8; ++kk)
        wreg[g][t2][kk] = *(const bf16x8*)&Whh[(size_t)(g * 256 + colw + t2 * 16 + m16) * 256
                                                + kk * 32 + quad * 8];
#pragma unroll
  for (int g = 0; g < 2; ++g)
#pragma unroll
    for (int t2 = 0; t2 < 2; ++t2)
#pragma unroll
      for (int kk = 0; kk < 8; ++kk)
        asm volatile("" : "+a"(wreg[g][t2][kk]));

  // n-gate stream pointers (waves whose cols are not in LDS)
  const unsigned short* WnG0 = &Whh[(size_t)(512 + colw + m16) * 256 + quad * 8];
  const unsigned short* WnG1 = WnG0 + 16 * 256;
  const int nb0 = (colw + m16) * 256;        // LDS base (ushort) for t2=0
  const int nb1 = nb0 + 4096;                // t2=1

  float bb_[3][2];
#pragma unroll
  for (int g = 0; g < 3; ++g)
#pragma unroll
    for (int t2 = 0; t2 < 2; ++t2)
      bb_[g][t2] = bhh[g * 256 + colw + t2 * 16 + m16];

  int rdoff[8];
#pragma unroll
  for (int kk = 0; kk < 8; ++kk)
    rdoff[kk] = m16 * 256 + (((kk * 4 + quad) ^ m16) * 8);
  int wroff0[4];
#pragma unroll
  for (int rg = 0; rg < 4; ++rg) {
    const int row = quad * 4 + rg;
    const int cb0 = w * 4 + (m16 >> 3);
    wroff0[rg] = row * 256 + ((cb0 ^ row) * 8) + (m16 & 7);
  }
  unsigned short* hp[4];
#pragma unroll
  for (int rg = 0; rg < 4; ++rg)
    hp[rg] = Hbf + (size_t)(b0 + quad * 4 + rg) * (TDIM * HIDN) + colw + m16;
  const float* gp = gi + (size_t)blockIdx.x * 128 * 12288 + (w * 256 + quad * 64 + m16 * 4);

  float hreg[2][4] = {};
  const f32x4 z4 = {0.f, 0.f, 0.f, 0.f};
  __syncthreads();

#define LDSN(base) (*(const bf16x8*)&ns[(base) + xo])
#define GLBN(p)    (*(const bf16x8*)&(p)[kk * 32])
#define KLOOP(N0E, N1E)                                                                   \
  _Pragma("unroll")                                                                       \
  for (int kk = 0; kk < 8; ++kk) {                                                        \
    const int xo = (((kk * 4 + quad) ^ m16) << 3); (void)xo;                              \
    const bf16x8 a = *(const bf16x8*)&hsr[rdoff[kk]];                                     \
    const bf16x8 n0 = (N0E); const bf16x8 n1 = (N1E);                                     \
    acc[0] = __builtin_amdgcn_mfma_f32_16x16x32_bf16(a, wreg[0][0][kk], acc[0], 0, 0, 0); \
    acc[1] = __builtin_amdgcn_mfma_f32_16x16x32_bf16(a, wreg[0][1][kk], acc[1], 0, 0, 0); \
    acc[2] = __builtin_amdgcn_mfma_f32_16x16x32_bf16(a, wreg[1][0][kk], acc[2], 0, 0, 0); \
    acc[3] = __builtin_amdgcn_mfma_f32_16x16x32_bf16(a, wreg[1][1][kk], acc[3], 0, 0, 0); \
    acc[4] = __builtin_amdgcn_mfma_f32_16x16x32_bf16(a, n0, acc[4], 0, 0, 0);             \
    acc[5] = __builtin_amdgcn_mfma_f32_16x16x32_bf16(a, n1, acc[5], 0, 0, 0);             \
  }

  for (int t = 0; t < TDIM; ++t) {
    const unsigned short* hsr = hs[t & 1];
    unsigned short*       hsw = hs[(t + 1) & 1];

    float4 gc[6];
#pragma unroll
    for (int c = 0; c < 6; ++c) gc[c] = *(const float4*)(gp + c * 2048);
    gp += 12288;

    f32x4 acc[6];
#pragma unroll
    for (int g = 0; g < 6; ++g) acc[g] = z4;

    if (w <= 1)      { KLOOP(LDSN(nb0), LDSN(nb1)) }    // n cols 0..63 in LDS
    else if (w == 2) { KLOOP(LDSN(nb0), GLBN(WnG1)) }   // cols 64..79 LDS, 80..95 stream
    else             { KLOOP(GLBN(WnG0), GLBN(WnG1)) }  // cols 96..255 stream

#pragma unroll
    for (int t2 = 0; t2 < 2; ++t2)
#pragma unroll
      for (int rg = 0; rg < 4; ++rg) {
        const float r = sigm(gc[t2][rg]     + acc[t2][rg]     + bb_[0][t2]);
        const float z = sigm(gc[2 + t2][rg] + acc[2 + t2][rg] + bb_[1][t2]);
        const float hn = acc[4 + t2][rg] + bb_[2][t2];
        const float n = tanh_f(gc[4 + t2][rg] + r * hn);
        float h = hreg[t2][rg];
        h = n + z * (h - n);                 // (1-z)*n + z*h
        hreg[t2][rg] = h;
        const unsigned short hb = f2bf(h);
        hsw[wroff0[rg] ^ (t2 << 4)] = hb;
        hp[rg][t2 * 16] = hb;
      }
#pragma unroll
    for (int rg = 0; rg < 4; ++rg) hp[rg] += 256;
    __syncthreads();   // h_{t+1} buffer complete before next step reads it
  }
#undef LDSN
#undef GLBN
#undef KLOOP
}

// ---------------- contrastive loss + alpha (bf16 WC & P) ----------------
__global__ __launch_bounds__(256) void loss_k(
    const unsigned short* __restrict__ WC, const unsigned short* __restrict__ P,
    const int* __restrict__ neg, float* __restrict__ alpha, float* __restrict__ loss)
{
  const int t = blockIdx.x;                       // 0..126
  const int w = threadIdx.x >> 6, lane = threadIdx.x & 63;
  __shared__ float wls[4];
  float lsum = 0.f;
#pragma unroll 1
  for (int bi = 0; bi < 8; ++bi) {
    const int b = blockIdx.y * 32 + w * 8 + bi;
    const ushort4 wcu = *(const ushort4*)&WC[(size_t)(b * TDIM + t) * DDIM + lane * 4];
    float wc0 = bf2f_s(wcu.x), wc1 = bf2f_s(wcu.y), wc2 = bf2f_s(wcu.z), wc3 = bf2f_s(wcu.w);
    float s[16];
    {
      const ushort4 p4 = *(const ushort4*)&P[(size_t)(b * TDIM + t + 1) * DDIM + lane * 4];
      s[0] = wc0 * bf2f_s(p4.x) + wc1 * bf2f_s(p4.y) + wc2 * bf2f_s(p4.z) + wc3 * bf2f_s(p4.w);
    }
#pragma unroll
    for (int n = 0; n < 15; ++n) {
      const int rb = neg[(t * 15 + n) * 256 + b];
      const ushort4 p4 = *(const ushort4*)&P[(size_t)(rb * TDIM + t + 1) * DDIM + lane * 4];
      s[n + 1] = wc0 * bf2f_s(p4.x) + wc1 * bf2f_s(p4.y) + wc2 * bf2f_s(p4.z) + wc3 * bf2f_s(p4.w);
    }
#pragma unroll
    for (int n = 0; n < 16; ++n) {
      float v = s[n];
#pragma unroll
      for (int off = 32; off > 0; off >>= 1) v += __shfl_xor(v, off);
      s[n] = v * (1.f / 256.f);                   // mean over D
    }
    float mx = s[0];
#pragma unroll
    for (int n = 1; n < 16; ++n) mx = fmaxf(mx, s[n]);
    float se = 0.f;
#pragma unroll
    for (int n = 0; n < 16; ++n) se += __expf(s[n] - mx);
    lsum -= (s[0] - mx - __logf(se));             // -pos_ce
    if (t == TDIM - 2 && lane == 0) alpha[b] = s[0];   // alpha == sp[:,126]
  }
  if (lane == 0) wls[w] = lsum;
  __syncthreads();
  if (threadIdx.x == 0)
    atomicAdd(loss, (wls[0] + wls[1] + wls[2] + wls[3]) * (1.f / 256.f));
}

// ---------------- y = gelu(H[:,-1]@Wp1^T) @ Wp2^T (second half) ----------------
__global__ __launch_bounds__(256) void y_k(const float* __restrict__ Yh,
                                           const float* __restrict__ Wp2,
                                           float* __restrict__ y) {
  const int w = threadIdx.x >> 6, lane = threadIdx.x & 63;
  const int b = blockIdx.x * 4 + w;
  const float4 a = *(const float4*)&Yh[(size_t)b * 256 + lane * 4];
  const float4 q = *(const float4*)&Wp2[lane * 4];
  float s = a.x * q.x + a.y * q.y + a.z * q.z + a.w * q.w;
#pragma unroll
  for (int off = 32; off > 0; off >>= 1) s += __shfl_xor(s, off);
  if (lane == 0) y[b] = s;
}

// ---------------- launch ----------------
extern "C" void kernel_launch(void* const* d_in, const int* in_sizes, int n_in,
                              void* d_out, int out_size, void* d_ws, size_t ws_size,
                              hipStream_t stream) {
  (void)in_sizes; (void)n_in; (void)out_size; (void)ws_size;
  const float* P    = (const float*)d_in[0];
  const float* bih0 = (const float*)d_in[3];
  const float* bhh0 = (const float*)d_in[4];
  const float* bih1 = (const float*)d_in[7];
  const float* bhh1 = (const float*)d_in[8];

  char* ws = (char*)d_ws;
  float*          gi   = (float*)(ws + 0);                       // 100663296 B (later: G1bf)
  unsigned short* Xbf  = (unsigned short*)(ws + 100663296);      // 16777216 B (H1bf then Hbf)
  unsigned short* Pbf  = (unsigned short*)(ws + 117440512);      // 16777216 B
  unsigned short* WCb  = (unsigned short*)(ws + 134217728);      // 16777216 B (bf16 WC)
  unsigned short* wb   = (unsigned short*)(ws + 167772160);      // bf16 weights
  unsigned short* wih0b = wb;
  unsigned short* whh0b = wb + 196608;
  unsigned short* wih1b = wb + 393216;
  unsigned short* whh1b = wb + 589824;
  unsigned short* wbW   = wb + 786432;
  unsigned short* wp1b  = wb + 851968;
  unsigned short* wr1b  = wb + 917504;
  unsigned short* wr2b  = wb + 983040;
  float*          Yh   = (float*)(ws + 169869312);               // 262144 B
  unsigned short* G1bf = (unsigned short*)gi;                    // reuse gi region after L1

  float* out  = (float*)d_out;
  float* Hout = out;                  // 8388608
  float* Yout = out + 8388608;        // 256
  float* Rout = out + 8388864;        // 8388608
  float* Aout = out + 16777472;       // 256
  float* Lout = out + 16777728;       // 1

  cvt_all<<<8448, 256, 0, stream>>>(
      P, Pbf,
      (const float*)d_in[1], wih0b, (const float*)d_in[2], whh0b,
      (const float*)d_in[5], wih1b, (const float*)d_in[6], whh1b,
      (const float*)d_in[9], wbW,   (const float*)d_in[10], wp1b,
      (const float*)d_in[12], wr1b, (const float*)d_in[13], wr2b);

  dim3 thr(256);
  // gi0 = Pbf @ Wih0^T + bih0   (tiled output)
  gemm_bf16<<<dim3(6, 256), thr, 0, stream>>>(Pbf, 256, wih0b, 256, bih0, gi, nullptr, 256, 768, 0, 1);
  // layer 0 recurrence -> H1bf
  gru_rec<<<16, 512, 0, stream>>>(gi, whh0b, bhh0, Xbf);
  // gi1 = H1bf @ Wih1^T + bih1  (tiled output)
  gemm_bf16<<<dim3(6, 256), thr, 0, stream>>>(Xbf, 256, wih1b, 256, bih1, gi, nullptr, 256, 768, 0, 1);
  // layer 1 recurrence -> Hbf
  gru_rec<<<16, 512, 0, stream>>>(gi, whh1b, bhh1, Xbf);
  // Hout fp32 = expand(Hbf)
  bf2f<<<8192, 256, 0, stream>>>(Xbf, Hout, 2097152);
  // WCbf = bf16(H @ W^T)
  gemm_bf16<<<dim3(2, 256), thr, 0, stream>>>(Xbf, 256, wbW, 256, nullptr, nullptr, WCb, 256, 256, 0, 0);
  // G1 = gelu(H @ Wr1^T) bf16 (into old gi region; Pbf still needed by loss)
  gemm_bf16<<<dim3(2, 256), thr, 0, stream>>>(Xbf, 256, wr1b, 256, nullptr, nullptr, G1bf, 256, 256, 1, 0);
  // R = G1 @ Wr2^T
  gemm_bf16<<<dim3(2, 256), thr, 0, stream>>>(G1bf, 256, wr2b, 256, nullptr, Rout, nullptr, 256, 256, 0, 0);
  // Yh = gelu(H[:,127,:] @ Wp1^T)  (A rows strided by T*HID)
  gemm_bf16<<<dim3(2, 2), thr, 0, stream>>>(Xbf + 127 * 256, 32768, wp1b, 256, nullptr, Yh, nullptr, 256, 256, 1, 0);
  y_k<<<64, 256, 0, stream>>>(Yh, (const float*)d_in[11], Yout);

  hipMemsetAsync(Lout, 0, 4, stream);
  loss_k<<<dim3(127, 8), thr, 0, stream>>>(WCb, Pbf, (const int*)d_in[14], Aout, Lout);
}